// Round 2
// baseline (531.165 us; speedup 1.0000x reference)
//
#include <hip/hip_runtime.h>
#include <math.h>

// ArcFaceLoss: B=512, D=512, C=100000, margin=0.5, scale=64
// R2: two-pass. prep_w streams W fp32 once -> normalized bf16, packed+swizzled.
// gemm_lse is pure bf16 MFMA with BOTH operands via global_load_lds width-16,
// M=256 x N=64 tiles, 4 blocks/CU, XOR-swizzled LDS (conflict-free ds_read_b128).

#define NB 512
#define ND 512
#define NC 100000
#define BK 32
#define NCHUNK 16            // ND / BK
#define CT 64                // classes per tile
#define MT 256               // batch rows per block
#define NCT 1563             // ceil(NC/CT); padded classes = 100032
#define FSCALE 64.0f
#define C_COS_M 0.8775825618903728f
#define C_SIN_M 0.479425538604203f
#define C_TH  (-0.8775825618903728f)
#define C_MM  0.2397127693021015f

typedef __bf16 bf16x8 __attribute__((ext_vector_type(8)));
typedef __bf16 bf16x4 __attribute__((ext_vector_type(4)));
typedef float  f32x4  __attribute__((ext_vector_type(4)));
typedef __attribute__((address_space(1))) unsigned int GU;
typedef __attribute__((address_space(3))) unsigned int LU;

// xp layout: [mh][chunk i][row r(0..255)][32k as 4 swizzled 16B granules]
// wp layout: [class-tile ct][chunk i][row r(0..63)][32k as 4 swizzled 16B granules]
// granule position = logical_granule ^ ((r>>1)&3)  -> 2 lanes/bank on ds_read_b128

// ---------------- 1) normalize + pack x ----------------
__global__ void pack_x_kernel(const float* __restrict__ x, __bf16* __restrict__ xp) {
  const int b = blockIdx.x;
  const int t = threadIdx.x;                   // 0..127, covers k=4t..4t+3
  float4 v = reinterpret_cast<const float4*>(x + (size_t)b * ND)[t];
  float ss = v.x*v.x + v.y*v.y + v.z*v.z + v.w*v.w;
  #pragma unroll
  for (int m = 1; m < 64; m <<= 1) ss += __shfl_xor(ss, m);
  __shared__ float sred[2];
  if ((t & 63) == 0) sred[t >> 6] = ss;
  __syncthreads();
  const float rn = rsqrtf(fmaxf(sred[0] + sred[1], 1e-24f));
  bf16x4 o;
  o[0] = (__bf16)(v.x * rn); o[1] = (__bf16)(v.y * rn);
  o[2] = (__bf16)(v.z * rn); o[3] = (__bf16)(v.w * rn);
  const int mh = b >> 8, r = b & 255;
  const int i  = t >> 3;                       // k-chunk
  const int g  = (t >> 1) & 3;                 // logical granule
  const int gp = g ^ ((r >> 1) & 3);           // swizzled position
  __bf16* dst = xp + ((size_t)(mh * NCHUNK + i) * MT + r) * BK + gp * 8 + (t & 1) * 4;
  *reinterpret_cast<bf16x4*>(dst) = o;
}

// ---------------- 2) stream-normalize W -> packed bf16 ----------------
__global__ __launch_bounds__(256) void prep_w_kernel(const float* __restrict__ w,
                                                     __bf16* __restrict__ wp) {
  const int b    = blockIdx.x;                 // 0..NCT-1, 64 classes each
  const int wv   = threadIdx.x >> 6;
  const int lane = threadIdx.x & 63;
  const int i = lane >> 2;                     // k-chunk (k = lane*8 -> k>>5)
  const int g = lane & 3;                      // logical granule
  for (int it = 0; it < 8; ++it) {
    #pragma unroll
    for (int h = 0; h < 2; ++h) {
      const int r = wv * 16 + h * 8 + it;      // 0..63
      const int c = b * CT + r;
      float4 v0 = {0.f,0.f,0.f,0.f}, v1 = {0.f,0.f,0.f,0.f};
      if (c < NC) {
        const float4* src = reinterpret_cast<const float4*>(w + (size_t)c * ND) + lane * 2;
        v0 = src[0]; v1 = src[1];
      }
      float ss = v0.x*v0.x + v0.y*v0.y + v0.z*v0.z + v0.w*v0.w
               + v1.x*v1.x + v1.y*v1.y + v1.z*v1.z + v1.w*v1.w;
      #pragma unroll
      for (int m = 1; m < 64; m <<= 1) ss += __shfl_xor(ss, m);
      const float rn = rsqrtf(fmaxf(ss, 1e-24f));   // pad rows: v==0 -> writes 0
      bf16x8 o;
      o[0] = (__bf16)(v0.x * rn); o[1] = (__bf16)(v0.y * rn);
      o[2] = (__bf16)(v0.z * rn); o[3] = (__bf16)(v0.w * rn);
      o[4] = (__bf16)(v1.x * rn); o[5] = (__bf16)(v1.y * rn);
      o[6] = (__bf16)(v1.z * rn); o[7] = (__bf16)(v1.w * rn);
      const int gp = g ^ ((r >> 1) & 3);
      __bf16* dst = wp + ((size_t)(b * NCHUNK + i) * CT + r) * BK + gp * 8;
      *reinterpret_cast<bf16x8*>(dst) = o;
    }
  }
}

// ---------------- 3) fp32-accurate target cosine + phi (+ gsum zero) ----------------
__global__ void cosphi_kernel(const float* __restrict__ x, const float* __restrict__ w,
                              const int* __restrict__ tgt,
                              float* __restrict__ cos_t, float* __restrict__ phi_t,
                              float* __restrict__ gsum) {
  const int b = blockIdx.x;
  const int lane = threadIdx.x;                // 0..63
  const int t = tgt[b];
  const float4* xr = reinterpret_cast<const float4*>(x + (size_t)b * ND);
  const float4* wr = reinterpret_cast<const float4*>(w + (size_t)t * ND);
  float dp = 0.f, xs = 0.f, ws = 0.f;
  #pragma unroll
  for (int j = 0; j < 2; ++j) {
    float4 xv = xr[lane * 2 + j];
    float4 wv = wr[lane * 2 + j];
    dp += xv.x*wv.x + xv.y*wv.y + xv.z*wv.z + xv.w*wv.w;
    xs += xv.x*xv.x + xv.y*xv.y + xv.z*xv.z + xv.w*xv.w;
    ws += wv.x*wv.x + wv.y*wv.y + wv.z*wv.z + wv.w*wv.w;
  }
  #pragma unroll
  for (int m = 1; m < 64; m <<= 1) {
    dp += __shfl_xor(dp, m);
    xs += __shfl_xor(xs, m);
    ws += __shfl_xor(ws, m);
  }
  if (lane == 0) {
    float c = dp * rsqrtf(fmaxf(xs, 1e-24f)) * rsqrtf(fmaxf(ws, 1e-24f));
    c = fminf(fmaxf(c, -1.f), 1.f);
    float s = sqrtf(fmaxf(1.f - c * c, 0.f));
    float phi = c * C_COS_M - s * C_SIN_M;
    phi = (c > C_TH) ? phi : (c - C_MM);
    cos_t[b] = c;
    phi_t[b] = phi;
    gsum[b] = 0.f;
  }
}

// ---------------- 4) bf16 GEMM + partial sum-exp ----------------
// Block: 256 threads (4 waves). Tile: 256 rows x 64 classes. BK=32, 16 chunks.
// Wave wv owns rows [64wv, 64wv+64) x all 64 classes: 4x4 of mfma 16x16x32.
__global__ __launch_bounds__(256, 4) void gemm_lse_kernel(
    const __bf16* __restrict__ xp, const __bf16* __restrict__ wp,
    float* __restrict__ gsum) {
  __shared__ __align__(16) __bf16 As[MT * BK];   // 16 KB
  __shared__ __align__(16) __bf16 Bs[CT * BK];   // 4 KB

  const int tid  = threadIdx.x;
  const int wv   = tid >> 6;
  const int lane = tid & 63;
  const int ct   = blockIdx.x >> 1;
  const int mh   = blockIdx.x & 1;

  const int ra  = lane & 15;
  const int q   = lane >> 4;
  const int gp  = q ^ ((ra >> 1) & 3);           // swizzled granule position

  const char* abase = reinterpret_cast<const char*>(xp) + (size_t)mh * (NCHUNK * MT * BK * 2);
  const char* bbase = reinterpret_cast<const char*>(wp) + (size_t)ct * (NCHUNK * CT * BK * 2);

  f32x4 acc[4][4] = {};

  for (int i = 0; i < NCHUNK; ++i) {
    __syncthreads();
    // stage A chunk: 16 KB, 4 x 1KB wave-segments per wave
    {
      const char* ga = abase + i * (MT * BK * 2) + wv * 4096 + lane * 16;
      char* la = reinterpret_cast<char*>(As) + wv * 4096;
      #pragma unroll
      for (int j = 0; j < 4; ++j)
        __builtin_amdgcn_global_load_lds((const GU*)(ga + j * 1024), (LU*)(la + j * 1024),
                                         16, 0, 0);
    }
    // stage B chunk: 4 KB, 1 x 1KB wave-segment per wave
    {
      const char* gb = bbase + i * (CT * BK * 2) + wv * 1024 + lane * 16;
      char* lb = reinterpret_cast<char*>(Bs) + wv * 1024;
      __builtin_amdgcn_global_load_lds((const GU*)gb, (LU*)lb, 16, 0, 0);
    }
    __syncthreads();

    bf16x8 af[4];
    #pragma unroll
    for (int rt = 0; rt < 4; ++rt)
      af[rt] = *reinterpret_cast<const bf16x8*>(As + (wv * 64 + rt * 16 + ra) * BK + gp * 8);
    #pragma unroll
    for (int c4 = 0; c4 < 4; ++c4) {
      bf16x8 bfr = *reinterpret_cast<const bf16x8*>(Bs + (c4 * 16 + ra) * BK + gp * 8);
      #pragma unroll
      for (int rt = 0; rt < 4; ++rt)
        acc[rt][c4] = __builtin_amdgcn_mfma_f32_16x16x32_bf16(af[rt], bfr, acc[rt][c4], 0, 0, 0);
    }
  }

  // epilogue: acc IS cosine (both operands pre-normalized).
  // C/D 16x16 layout: col = lane&15, row = (lane>>4)*4 + reg
  #pragma unroll
  for (int rt = 0; rt < 4; ++rt) {
    #pragma unroll
    for (int r = 0; r < 4; ++r) {
      float es = 0.f;
      #pragma unroll
      for (int c4 = 0; c4 < 4; ++c4)
        es += __expf(fmaf(FSCALE, acc[rt][c4][r], -FSCALE));
      es += __shfl_xor(es, 1);
      es += __shfl_xor(es, 2);
      es += __shfl_xor(es, 4);
      es += __shfl_xor(es, 8);
      if (ra == 0)
        atomicAdd(&gsum[mh * MT + wv * 64 + rt * 16 + q * 4 + r], es);
    }
  }
}

// ---------------- 5) finalize ----------------
__global__ void finalize_kernel(const float* __restrict__ gsum,
                                const float* __restrict__ cos_t,
                                const float* __restrict__ phi_t,
                                float* __restrict__ out) {
  const int b = threadIdx.x;   // 512
  const float c = cos_t[b];
  const float p = phi_t[b];
  float corr = gsum[b] - __expf(fmaf(FSCALE, c, -FSCALE))
                       + __expf(fmaf(FSCALE, p, -FSCALE));
  corr = fmaxf(corr, 1e-38f);
  float lb = FSCALE + logf(corr) - FSCALE * p;
  #pragma unroll
  for (int m = 1; m < 64; m <<= 1) lb += __shfl_xor(lb, m);
  __shared__ float pr[8];
  if ((b & 63) == 0) pr[b >> 6] = lb;
  __syncthreads();
  if (b == 0) {
    float tot = 0.f;
    #pragma unroll
    for (int j = 0; j < 8; ++j) tot += pr[j];
    out[0] = tot * (1.0f / NB);
  }
}

extern "C" void kernel_launch(void* const* d_in, const int* in_sizes, int n_in,
                              void* d_out, int out_size, void* d_ws, size_t ws_size,
                              hipStream_t stream) {
  const float* x  = (const float*)d_in[0];
  const float* w  = (const float*)d_in[1];
  const int* tgt  = (const int*)d_in[2];
  float* out      = (float*)d_out;

  // workspace: xp (512 KB) | wp (1563*64KB = 97.7 MB) | gsum | cos_t | phi_t
  const size_t XP_BYTES = (size_t)2 * NCHUNK * MT * BK * 2;       // 512 KB
  const size_t WP_BYTES = (size_t)NCT * NCHUNK * CT * BK * 2;     // ~100 MB
  __bf16* xp   = (__bf16*)d_ws;
  __bf16* wp   = (__bf16*)((char*)d_ws + XP_BYTES);
  float* gsum  = (float*)((char*)d_ws + XP_BYTES + WP_BYTES);
  float* cos_t = gsum + NB;
  float* phi_t = cos_t + NB;

  pack_x_kernel<<<NB, 128, 0, stream>>>(x, xp);
  prep_w_kernel<<<NCT, 256, 0, stream>>>(w, wp);
  cosphi_kernel<<<NB, 64, 0, stream>>>(x, w, tgt, cos_t, phi_t, gsum);
  gemm_lse_kernel<<<NCT * 2, 256, 0, stream>>>(xp, wp, gsum);
  finalize_kernel<<<1, 512, 0, stream>>>(gsum, cos_t, phi_t, out);
}